// Round 4
// baseline (239.006 us; speedup 1.0000x reference)
//
#include <hip/hip_runtime.h>

// LocalSorterModel, fully collapsed + bf16 MFMA:
//   out[b,r] = sum_x E[b,x] * W[x,r] + const[r],  x = n*1024+d, K=5120
//   W built by fold GEMM: C[d][n*128+r] = sum_k2 Afold[d][k2]*C2R[n*128+r][k2]
//     Afold[d][k2]  = pw_w[k2&1023][(k2>>10)*1024 + d]       (bf16, K-contig)
//     C2R[col][k2]  = CA[r,n,k2] (k2<1024) | CB[r,n,k2-1024]  (bf16, K-contig)
//   WTt[r][x] bf16 (K-contig) feeds main GEMM B-operand.
//   const[r] = cls_b[r] + sum_k pw_b[k] * sum_n CA[r,n,k]
// MFMA 16x16x32 bf16; LDS tiles 128x64 bf16, XOR swizzle slot^=(row&7).

#define NR 120
#define KXX 5120
#define PM_SLICE (2048*128)

typedef __attribute__((ext_vector_type(8))) short bf8;
typedef __attribute__((ext_vector_type(4))) float f4;

__device__ __forceinline__ unsigned int f2bf(float f) {
    unsigned int x = __builtin_bit_cast(unsigned int, f);
    return (x + 0x7fffu + ((x >> 16) & 1u)) >> 16;   // RNE bf16 bits in low 16
}
__device__ __forceinline__ float bf2f(unsigned short u) {
    unsigned int x = ((unsigned int)u) << 16;
    return __builtin_bit_cast(float, x);
}

// ---- C2R: [640 col][2048 k2] bf16, col = n*128+r (r>=120 zero) ----
__global__ __launch_bounds__(256) void k_prep(const float* __restrict__ cls_w,
                                              unsigned short* __restrict__ C2R) {
    const int col = blockIdx.x, half = blockIdx.y, t = threadIdx.x;
    const int n = col >> 7, r = col & 127;
    unsigned short* dst = C2R + (size_t)col * 2048 + half * 1024 + t * 4;
    if (r >= NR) { *(unsigned long long*)dst = 0ull; return; }
    const float* base = cls_w + (size_t)r * 20480 + t * 4;
    float sx = 0, sy = 0, sz = 0, sw = 0;
    if (half == 0) {
        #pragma unroll
        for (int q = 0; q < 4; q++) {
            float4 v = *(const float4*)(base + (4 * n + q) * 1024);
            sx += v.x; sy += v.y; sz += v.z; sw += v.w;
        }
    } else {
        #pragma unroll
        for (int i = 0; i < 5; i++) {
            if (i == n) continue;
            int q = (n > i) ? (n - 1) : n;
            float4 v = *(const float4*)(base + (4 * i + q) * 1024);
            sx += v.x; sy += v.y; sz += v.z; sw += v.w;
        }
    }
    unsigned long long pk = (unsigned long long)f2bf(sx)
                          | ((unsigned long long)f2bf(sy) << 16)
                          | ((unsigned long long)f2bf(sz) << 32)
                          | ((unsigned long long)f2bf(sw) << 48);
    *(unsigned long long*)dst = pk;
}

// ---- Afold: [1024 d][2048 k2] bf16 = transposed/interleaved pw_w ----
__global__ __launch_bounds__(256) void k_wprep(const float* __restrict__ pw_w,
                                               unsigned short* __restrict__ Afold) {
    __shared__ float T[64][65];
    const int d0 = blockIdx.x * 64, kt0 = blockIdx.y * 64;
    const int h = blockIdx.y >> 4, kr0 = (blockIdx.y & 15) * 64;
    const int t = threadIdx.x;
    #pragma unroll
    for (int lp = 0; lp < 4; lp++) {
        int lk = lp * 16 + (t >> 4);
        float4 v = *(const float4*)(pw_w + (size_t)(kr0 + lk) * 2048 + h * 1024 + d0 + (t & 15) * 4);
        T[lk][(t & 15) * 4 + 0] = v.x; T[lk][(t & 15) * 4 + 1] = v.y;
        T[lk][(t & 15) * 4 + 2] = v.z; T[lk][(t & 15) * 4 + 3] = v.w;
    }
    __syncthreads();
    #pragma unroll
    for (int wp = 0; wp < 2; wp++) {
        int ld = wp * 32 + (t >> 3);
        int lk2 = (t & 7) * 8;
        uint4 o;
        o.x = f2bf(T[lk2 + 0][ld]) | (f2bf(T[lk2 + 1][ld]) << 16);
        o.y = f2bf(T[lk2 + 2][ld]) | (f2bf(T[lk2 + 3][ld]) << 16);
        o.z = f2bf(T[lk2 + 4][ld]) | (f2bf(T[lk2 + 5][ld]) << 16);
        o.w = f2bf(T[lk2 + 6][ld]) | (f2bf(T[lk2 + 7][ld]) << 16);
        *(uint4*)(Afold + (size_t)(d0 + ld) * 2048 + kt0 + lk2) = o;
    }
}

__global__ __launch_bounds__(256) void k_const(const unsigned short* __restrict__ C2R,
                                               const float* __restrict__ pw_b,
                                               const float* __restrict__ cls_b,
                                               float* __restrict__ constv) {
    const int r = blockIdx.x, t = threadIdx.x;
    float acc = 0.f;
    for (int k = t; k < 1024; k += 256) {
        float s = 0.f;
        #pragma unroll
        for (int n = 0; n < 5; n++) s += bf2f(C2R[(size_t)(n * 128 + r) * 2048 + k]);
        acc += s * pw_b[k];
    }
    __shared__ float red[256];
    red[t] = acc; __syncthreads();
    for (int s2 = 128; s2 > 0; s2 >>= 1) {
        if (t < s2) red[t] += red[t + s2];
        __syncthreads();
    }
    if (t == 0) constv[r] = cls_b[r] + red[0];
}

// ---- fold GEMM (MFMA): 40 blocks, full K=2048, emits WTt[128 r][5120] bf16 ----
__global__ __launch_bounds__(256) void k_fold(const unsigned short* __restrict__ Afold,
                                              const unsigned short* __restrict__ C2R,
                                              unsigned short* __restrict__ WTt) {
    __shared__ __align__(16) unsigned short lds[2 * 128 * 64];
    unsigned short* Al = lds;
    unsigned short* Bl = lds + 128 * 64;
    const int d0 = blockIdx.x * 128, n = blockIdx.y;
    const int t = threadIdx.x, lane = t & 63, wv = t >> 6;
    const int wm = wv >> 1, wn = wv & 1;
    const int srow = t & 127, sgrp = t >> 7;

    f4 acc[4][4];
    #pragma unroll
    for (int i = 0; i < 4; i++)
        #pragma unroll
        for (int j = 0; j < 4; j++) acc[i][j] = (f4){0.f, 0.f, 0.f, 0.f};

    const unsigned short* Ag = Afold + (size_t)(d0 + srow) * 2048;
    const unsigned short* Bg = C2R + (size_t)(n * 128 + srow) * 2048;
    uint4 ra[4], rb[4];
    #pragma unroll
    for (int u = 0; u < 4; u++) {
        int sl = sgrp * 4 + u;
        ra[u] = *(const uint4*)(Ag + sl * 8);
        rb[u] = *(const uint4*)(Bg + sl * 8);
    }
    for (int kt = 0; kt < 32; kt++) {
        if (kt) __syncthreads();
        #pragma unroll
        for (int u = 0; u < 4; u++) {
            int sl = sgrp * 4 + u;
            *(uint4*)(Al + srow * 64 + ((sl ^ (srow & 7)) * 8)) = ra[u];
            *(uint4*)(Bl + srow * 64 + ((sl ^ (srow & 7)) * 8)) = rb[u];
        }
        __syncthreads();
        if (kt + 1 < 32) {
            int kb = (kt + 1) * 64;
            #pragma unroll
            for (int u = 0; u < 4; u++) {
                int sl = sgrp * 4 + u;
                ra[u] = *(const uint4*)(Ag + kb + sl * 8);
                rb[u] = *(const uint4*)(Bg + kb + sl * 8);
            }
        }
        #pragma unroll
        for (int s = 0; s < 2; s++) {
            bf8 af[4], bq[4];
            #pragma unroll
            for (int f = 0; f < 4; f++) {
                int rowa = wm * 64 + f * 16 + (lane & 15);
                int sla = (s * 4 + (lane >> 4)) ^ (rowa & 7);
                af[f] = *reinterpret_cast<const bf8*>(Al + rowa * 64 + sla * 8);
                int rowb = wn * 64 + f * 16 + (lane & 15);
                int slb = (s * 4 + (lane >> 4)) ^ (rowb & 7);
                bq[f] = *reinterpret_cast<const bf8*>(Bl + rowb * 64 + slb * 8);
            }
            #pragma unroll
            for (int i = 0; i < 4; i++)
                #pragma unroll
                for (int j = 0; j < 4; j++)
                    acc[i][j] = __builtin_amdgcn_mfma_f32_16x16x32_bf16(af[i], bq[j], acc[i][j], 0, 0, 0);
        }
    }
    // repack D (rows=d, cols=colr) -> LDS T[128 col][128 d] bf16, then coalesced WTt store
    __syncthreads();
    unsigned short* T = lds;
    #pragma unroll
    for (int i = 0; i < 4; i++) {
        int dbase = wm * 64 + i * 16 + (lane >> 4) * 4;
        #pragma unroll
        for (int j = 0; j < 4; j++) {
            int cl = wn * 64 + j * 16 + (lane & 15);
            unsigned long long pk = (unsigned long long)f2bf(acc[i][j][0])
                                  | ((unsigned long long)f2bf(acc[i][j][1]) << 16)
                                  | ((unsigned long long)f2bf(acc[i][j][2]) << 32)
                                  | ((unsigned long long)f2bf(acc[i][j][3]) << 48);
            *(unsigned long long*)(T + cl * 128 + dbase) = pk;
        }
    }
    __syncthreads();
    #pragma unroll
    for (int rep = 0; rep < 4; rep++) {
        int c = rep * 32 + (t >> 3);
        int db = (t & 7) * 16;
        uint4 v0 = *(const uint4*)(T + c * 128 + db);
        uint4 v1 = *(const uint4*)(T + c * 128 + db + 8);
        unsigned short* w = WTt + (size_t)c * 5120 + n * 1024 + d0 + db;
        *(uint4*)w = v0;
        *(uint4*)(w + 8) = v1;
    }
}

// ---- main GEMM (MFMA): A=E fp32 (cvt in staging), B=WTt bf16; partials fp32 ----
__global__ __launch_bounds__(256) void k_main(const float* __restrict__ E,
                                              const unsigned short* __restrict__ WTt,
                                              float* __restrict__ Pm, int kchunk) {
    __shared__ __align__(16) unsigned short lds[2 * 128 * 64];
    unsigned short* Al = lds;
    unsigned short* Bl = lds + 128 * 64;
    const int m0 = blockIdx.x * 128;
    const int kc0 = blockIdx.y * kchunk;
    const int t = threadIdx.x, lane = t & 63, wv = t >> 6;
    const int wm = wv >> 1, wn = wv & 1;
    const int srow = t & 127, sgrp = t >> 7;

    f4 acc[4][4];
    #pragma unroll
    for (int i = 0; i < 4; i++)
        #pragma unroll
        for (int j = 0; j < 4; j++) acc[i][j] = (f4){0.f, 0.f, 0.f, 0.f};

    const float* Ag = E + (size_t)(m0 + srow) * KXX + kc0;
    const unsigned short* Bg = WTt + (size_t)srow * KXX + kc0;
    float4 ra[8];
    uint4 rb[4];
    const int nst = kchunk >> 6;
    #pragma unroll
    for (int u = 0; u < 8; u++) ra[u] = *(const float4*)(Ag + sgrp * 32 + u * 4);
    #pragma unroll
    for (int u = 0; u < 4; u++) rb[u] = *(const uint4*)(Bg + (sgrp * 4 + u) * 8);

    for (int kt = 0; kt < nst; kt++) {
        if (kt) __syncthreads();
        #pragma unroll
        for (int u = 0; u < 4; u++) {
            int sl = sgrp * 4 + u;
            float4 v0 = ra[2 * u], v1 = ra[2 * u + 1];
            uint4 o;
            o.x = f2bf(v0.x) | (f2bf(v0.y) << 16);
            o.y = f2bf(v0.z) | (f2bf(v0.w) << 16);
            o.z = f2bf(v1.x) | (f2bf(v1.y) << 16);
            o.w = f2bf(v1.z) | (f2bf(v1.w) << 16);
            *(uint4*)(Al + srow * 64 + ((sl ^ (srow & 7)) * 8)) = o;
            *(uint4*)(Bl + srow * 64 + ((sl ^ (srow & 7)) * 8)) = rb[u];
        }
        __syncthreads();
        if (kt + 1 < nst) {
            int kb = (kt + 1) * 64;
            #pragma unroll
            for (int u = 0; u < 8; u++) ra[u] = *(const float4*)(Ag + kb + sgrp * 32 + u * 4);
            #pragma unroll
            for (int u = 0; u < 4; u++) rb[u] = *(const uint4*)(Bg + kb + (sgrp * 4 + u) * 8);
        }
        #pragma unroll
        for (int s = 0; s < 2; s++) {
            bf8 af[4], bq[4];
            #pragma unroll
            for (int f = 0; f < 4; f++) {
                int rowa = wm * 64 + f * 16 + (lane & 15);
                int sla = (s * 4 + (lane >> 4)) ^ (rowa & 7);
                af[f] = *reinterpret_cast<const bf8*>(Al + rowa * 64 + sla * 8);
                int rowb = wn * 64 + f * 16 + (lane & 15);
                int slb = (s * 4 + (lane >> 4)) ^ (rowb & 7);
                bq[f] = *reinterpret_cast<const bf8*>(Bl + rowb * 64 + slb * 8);
            }
            #pragma unroll
            for (int i = 0; i < 4; i++)
                #pragma unroll
                for (int j = 0; j < 4; j++)
                    acc[i][j] = __builtin_amdgcn_mfma_f32_16x16x32_bf16(af[i], bq[j], acc[i][j], 0, 0, 0);
        }
    }
    float* dst = Pm + (size_t)blockIdx.y * PM_SLICE;
    #pragma unroll
    for (int i = 0; i < 4; i++) {
        int row = m0 + wm * 64 + i * 16 + (lane >> 4) * 4;
        #pragma unroll
        for (int j = 0; j < 4; j++) {
            int col = wn * 64 + j * 16 + (lane & 15);
            #pragma unroll
            for (int q = 0; q < 4; q++)
                dst[(size_t)(row + q) * 128 + col] = acc[i][j][q];
        }
    }
}

__global__ __launch_bounds__(256) void k_mainred(const float* __restrict__ Pm,
                                                 const float* __restrict__ constv,
                                                 float* __restrict__ out, int nksm) {
    int tid = blockIdx.x * 256 + threadIdx.x;   // 2048*120 = 245760
    int b = tid / NR, r = tid - b * NR;
    float s = constv[r];
    for (int ks = 0; ks < nksm; ks++)
        s += Pm[(size_t)ks * PM_SLICE + (size_t)b * 128 + r];
    out[tid] = s;
}

extern "C" void kernel_launch(void* const* d_in, const int* in_sizes, int n_in,
                              void* d_out, int out_size, void* d_ws, size_t ws_size,
                              hipStream_t stream) {
    const float* embeds = (const float*)d_in[0];  // [2048][5][1024]
    const float* pw_w   = (const float*)d_in[1];  // [1024][2048]
    const float* pw_b   = (const float*)d_in[2];  // [1024]
    const float* cls_w  = (const float*)d_in[3];  // [120][20480]
    const float* cls_b  = (const float*)d_in[4];  // [120]
    float* out = (float*)d_out;                   // [2048][120]

    unsigned short* C2R   = (unsigned short*)d_ws;          // 640*2048 bf16
    unsigned short* Afold = C2R + (size_t)640 * 2048;       // 1024*2048 bf16
    unsigned short* WTt   = Afold + (size_t)1024 * 2048;    // 128*5120 bf16
    float* constv = (float*)(WTt + (size_t)128 * 5120);     // 128 f32
    float* Pm = constv + 128;

    size_t used = ((size_t)640 * 2048 + (size_t)1024 * 2048 + (size_t)128 * 5120) * 2 + 512;
    size_t avail = (ws_size > used) ? (ws_size - used) / 4 : 0;
    int nksm = 16;
    while (nksm > 1 && (size_t)nksm * PM_SLICE > avail) nksm >>= 1;
    int kchunk = KXX / nksm;

    k_prep<<<dim3(640, 2), dim3(256), 0, stream>>>(cls_w, C2R);
    k_wprep<<<dim3(16, 32), dim3(256), 0, stream>>>(pw_w, Afold);
    k_const<<<dim3(NR), dim3(256), 0, stream>>>(C2R, pw_b, cls_b, constv);
    k_fold<<<dim3(8, 5), dim3(256), 0, stream>>>(Afold, C2R, WTt);
    k_main<<<dim3(16, nksm), dim3(256), 0, stream>>>(embeds, WTt, Pm, kchunk);
    k_mainred<<<dim3(960), dim3(256), 0, stream>>>(Pm, constv, out, nksm);
}